// Round 4
// baseline (1406.894 us; speedup 1.0000x reference)
//
#include <hip/hip_runtime.h>
#include <hip/hip_bf16.h>
#include <stdint.h>

typedef __hip_bfloat16 bf16_t;
typedef __attribute__((ext_vector_type(4))) float f32x4;
typedef __attribute__((ext_vector_type(8))) short s16x8;

#define UNITS 768
#define NCOLS 3072        // 4*UNITS (gates, reordered)
#define NPRED 96
#define MROWS 2048
#define BM 128
#define BN 128
#define BK 32

// s_waitcnt imm: vmcnt[3:0]=b0-3, expcnt=b4-6, lgkmcnt=b8-11, vmcnt[5:4]=b14-15
#define WAIT_VMCNT8 0xF78   // vmcnt(8), expcnt/lgkmcnt unconstrained

// async global->LDS, 16B per lane, LDS dest = wave-uniform base + lane*16
#define GLL16(ldsp, gp) \
  __builtin_amdgcn_global_load_lds((const __attribute__((address_space(1))) void*)(gp), \
                                   (__attribute__((address_space(3))) void*)(ldsp), 16, 0, 0)

__device__ __forceinline__ float sigf(float x) {
    return __builtin_amdgcn_rcpf(1.f + __expf(-x));
}
__device__ __forceinline__ float tanh_fast(float x) {
    return 1.f - 2.f * __builtin_amdgcn_rcpf(1.f + __expf(2.f * x));
}

// ---------------- prep kernels (once per launch, off critical path) ---------------

__global__ void prep_b0(const float* __restrict__ W_ih, bf16_t* __restrict__ B0T) {
    int idx = blockIdx.x * 256 + threadIdx.x;
    if (idx >= NCOLS * 96) return;
    int c = idx / 96, k = idx % 96;
    int u = ((c >> 6) << 4) + (c & 15);
    int g = (c >> 4) & 3;
    B0T[idx] = (bf16_t)W_ih[(g * UNITS + u) * 96 + k];
}

__global__ void prep_x0(const float* __restrict__ inputs, bf16_t* __restrict__ x0) {
    int idx = blockIdx.x * 256 + threadIdx.x; // < 2048*96 exactly
    int b = idx / 96, k = idx % 96;
    x0[idx] = (bf16_t)inputs[(b * 24 + 23) * 96 + k];
}

__global__ void prep_bias(const float* __restrict__ b_ih, const float* __restrict__ b_hh,
                          const float* __restrict__ W_ih, const float* __restrict__ b_d,
                          float* __restrict__ b0_r, float* __restrict__ beff_r) {
    int c = blockIdx.x * 256 + threadIdx.x;
    if (c >= NCOLS) return;
    int u = ((c >> 6) << 4) + (c & 15);
    int g = (c >> 4) & 3;
    int r = g * UNITS + u;
    float v = b_ih[r] + b_hh[r];
    float acc = 0.f;
    for (int j = 0; j < 96; ++j) acc += W_ih[r * 96 + j] * b_d[j];
    b0_r[c] = v;
    beff_r[c] = v + acc;
}

// BeffT[c][k] = W_hh[r(c)][k] + sum_j W_ih[r(c)][j]*W_d[j][k]   (c<3072, LDS-tiled)
__global__ void prep_beff2(const float* __restrict__ W_hh, const float* __restrict__ W_ih,
                           const float* __restrict__ W_d, bf16_t* __restrict__ BeffT) {
    __shared__ float sWih[64][96];
    __shared__ float sWd[96][64];
    const int c0 = blockIdx.x * 64, k0 = blockIdx.y * 64;
    const int tid = threadIdx.x;
    for (int i = tid; i < 64 * 96; i += 256) {
        int cc = i / 96, j = i % 96;
        int c = c0 + cc;
        int u = ((c >> 6) << 4) + (c & 15);
        int g = (c >> 4) & 3;
        sWih[cc][j] = W_ih[(g * UNITS + u) * 96 + j];
    }
    for (int i = tid; i < 96 * 64; i += 256) {
        int j = i / 64, kk = i % 64;
        sWd[j][kk] = W_d[j * UNITS + k0 + kk];
    }
    __syncthreads();
    const int kk = tid & 63;
    const int cc0 = (tid >> 6) * 16;
    for (int cc = cc0; cc < cc0 + 16; ++cc) {
        float acc = 0.f;
#pragma unroll 12
        for (int j = 0; j < 96; ++j) acc += sWih[cc][j] * sWd[j][kk];
        int c = c0 + cc;
        int u = ((c >> 6) << 4) + (c & 15);
        int g = (c >> 4) & 3;
        int r = g * UNITS + u;
        BeffT[(size_t)c * UNITS + k0 + kk] = (bf16_t)(W_hh[(size_t)r * UNITS + k0 + kk] + acc);
    }
}

// rows 3072..3199 of BeffT: W_d rows then zero pad
__global__ void prep_wdt(const float* __restrict__ W_d, bf16_t* __restrict__ BeffT) {
    int idx = blockIdx.x * 256 + threadIdx.x; // 128*768
    int c = idx / UNITS, k = idx % UNITS;
    float v = (c < NPRED) ? W_d[c * UNITS + k] : 0.f;
    BeffT[(size_t)(NCOLS + c) * UNITS + k] = (bf16_t)v;
}

// ---------------- main step kernel: 3-deep pipelined K-loop, raw barrier ---------------
// grid 1-D (n_tiles, divisible by 8). XCD swizzle: blk%8 -> XCD, consecutive global
// tile ids g within an XCD share N-tiles (B-panel slice fits that XCD's L2).
// g = (blk&7)*(grid/8) + blk>>3;  nt = nt_off + g/16;  mt = g%16.
//
// K-loop: 4 LDS buffer pairs; at kt wait own vmcnt(8) (stages kt+1,kt+2 in flight),
// raw s_barrier (no vmcnt(0) drain), ds_read frags(buf kt%4), stage kt+3, 16 MFMA.
// Tail stages are clamped re-loads to keep vmcnt accounting uniform.
// c-state layout: [slot=nt*16+mt][wave][lane][16] fp32 -> per-lane contiguous float4 x4.
__global__ __launch_bounds__(256, 2)
void step_kernel(const bf16_t* __restrict__ A,
                 const bf16_t* __restrict__ BT,
                 const float* __restrict__ bias_r,
                 const float* __restrict__ b_d,
                 float* __restrict__ c_state,
                 bf16_t* __restrict__ h_out,
                 float* __restrict__ out,
                 int Kdim, int nt_off, int t, int is_first)
{
    __shared__ bf16_t sAll[4][2][BM * BK];   // [buf][A/B][tile]; 64 KB total

    const int tid = threadIdx.x;
    const int wave = tid >> 6;
    const int lane = tid & 63;
    const int wr = wave >> 1, wc = wave & 1;
    const int l15 = lane & 15, l4 = lane >> 4;

    const int per = gridDim.x >> 3;
    const int g = (blockIdx.x & 7) * per + (blockIdx.x >> 3);
    const int nt = nt_off + (g >> 4);
    const int mt = g & 15;
    const int m0 = mt * BM;
    const int n0 = nt * BN;
    const bool is_pred = (nt >= 24);

    // ---- pre-loop operand loads (pinned before staging for vmcnt accounting) ----
    const int u = nt * 32 + wc * 16 + l15;
    const int slot = nt * 16 + mt;            // gate tiles only use c
    float* cbase = c_state + (((size_t)slot * 4 + wave) * 64 + lane) * 16;
    f32x4 cold4[4];
    float bi[4];
#pragma unroll
    for (int q = 0; q < 4; ++q) cold4[q] = f32x4{0.f, 0.f, 0.f, 0.f};
    if (!is_pred) {
        if (!is_first) {
#pragma unroll
            for (int q = 0; q < 4; ++q) cold4[q] = *(const f32x4*)(cbase + q * 4);
        }
#pragma unroll
        for (int f = 0; f < 4; ++f) bi[f] = bias_r[n0 + wc * 64 + f * 16 + l15];
    } else {
#pragma unroll
        for (int f = 0; f < 4; ++f) {
            int j = wc * 64 + f * 16 + l15;
            bi[f] = (j < NPRED) ? b_d[j] : 0.f;
        }
    }
    asm volatile("" ::: "memory");   // pin pre-loads before stage(0)

    f32x4 acc[4][4];
#pragma unroll
    for (int i = 0; i < 4; ++i)
#pragma unroll
        for (int j = 0; j < 4; ++j) acc[i][j] = f32x4{0.f, 0.f, 0.f, 0.f};

    const int o0 = wave * 1024 + lane * 16;   // byte offset within 8KB tile
    const int nk = Kdim >> 5;

#define STAGE(BUF, KT) do {                                                         \
        const int _kt = ((KT) < nk) ? (KT) : (nk - 1);                              \
        const int _k0 = _kt << 5;                                                   \
        bf16_t* _dA = &sAll[(BUF)][0][0];                                           \
        bf16_t* _dB = &sAll[(BUF)][1][0];                                           \
        _Pragma("unroll")                                                           \
        for (int _r = 0; _r < 2; ++_r) {                                            \
            int _ob = o0 + _r * 4096;                                               \
            int _row = _ob >> 6;                                                    \
            int _kb = _ob & 63;                                                     \
            const bf16_t* _gA = A + (size_t)(m0 + _row) * Kdim + _k0 + (_kb >> 1);  \
            GLL16(_dA + ((wave * 1024 + _r * 4096) >> 1), _gA);                     \
            const bf16_t* _gB = BT + (size_t)(n0 + _row) * Kdim + _k0 + (_kb >> 1); \
            GLL16(_dB + ((wave * 1024 + _r * 4096) >> 1), _gB);                     \
        }                                                                           \
    } while (0)

    STAGE(0, 0);
    STAGE(1, 1);
    STAGE(2, 2);

    for (int kt = 0; kt < nk; ++kt) {
        __builtin_amdgcn_s_waitcnt(WAIT_VMCNT8);  // own stage(kt) landed; kt+1,kt+2 in flight
        __builtin_amdgcn_s_barrier();             // all waves' stage(kt) landed
        asm volatile("" ::: "memory");

        const int cb = kt & 3;
        const char* sAc = (const char*)&sAll[cb][0][0];
        const char* sBc = (const char*)&sAll[cb][1][0];

        s16x8 af[4], bfr[4];
#pragma unroll
        for (int f = 0; f < 4; ++f) {
            af[f]  = *(const s16x8*)(sAc + (wr * 64 + f * 16 + l15) * 64 + l4 * 16);
            bfr[f] = *(const s16x8*)(sBc + (wc * 64 + f * 16 + l15) * 64 + l4 * 16);
        }

        STAGE((kt + 3) & 3, kt + 3);   // clamped at tail: keeps 12 loads outstanding

#pragma unroll
        for (int i = 0; i < 4; ++i)
#pragma unroll
            for (int j = 0; j < 4; ++j)
                acc[i][j] = __builtin_amdgcn_mfma_f32_16x16x32_bf16(af[i], bfr[j], acc[i][j], 0, 0, 0);
    }
#undef STAGE

    // ---- epilogue ----
    if (!is_pred) {
        f32x4 cnew4[4];
#pragma unroll
        for (int i = 0; i < 4; ++i) {
#pragma unroll
            for (int r = 0; r < 4; ++r) {
                int row = m0 + wr * 64 + i * 16 + l4 * 4 + r;
                float gi = acc[i][0][r] + bi[0];
                float gf = acc[i][1][r] + bi[1];
                float gg = acc[i][2][r] + bi[2];
                float go = acc[i][3][r] + bi[3];
                float si = sigf(gi);
                float sf = sigf(gf);
                float tg = tanh_fast(gg);
                float so = sigf(go);
                float cn = sf * cold4[i][r] + si * tg;
                cnew4[i][r] = cn;
                h_out[(size_t)row * UNITS + u] = (bf16_t)(so * tanh_fast(cn));
            }
        }
#pragma unroll
        for (int q = 0; q < 4; ++q) *(f32x4*)(cbase + q * 4) = cnew4[q];
    } else {
#pragma unroll
        for (int f = 0; f < 4; ++f) {
            int j = wc * 64 + f * 16 + l15;
            if (j < NPRED) {
#pragma unroll
                for (int i = 0; i < 4; ++i)
#pragma unroll
                    for (int r = 0; r < 4; ++r) {
                        int row = m0 + wr * 64 + i * 16 + l4 * 4 + r;
                        out[((size_t)row * 64 + (t - 1)) * NPRED + j] = acc[i][f][r] + bi[f];
                    }
            }
        }
    }
}

extern "C" void kernel_launch(void* const* d_in, const int* in_sizes, int n_in,
                              void* d_out, int out_size, void* d_ws, size_t ws_size,
                              hipStream_t stream)
{
    const float* inputs = (const float*)d_in[0];
    const float* W_ih   = (const float*)d_in[1];
    const float* W_hh   = (const float*)d_in[2];
    const float* b_ih   = (const float*)d_in[3];
    const float* b_hh   = (const float*)d_in[4];
    const float* W_d    = (const float*)d_in[5];
    const float* b_d    = (const float*)d_in[6];
    float* out = (float*)d_out;

    char* ws = (char*)d_ws;
    size_t off = 0;
    auto alloc = [&](size_t bytes) -> char* {
        char* p = ws + off;
        off = (off + bytes + 255) & ~(size_t)255;
        return p;
    };
    bf16_t* B0T   = (bf16_t*)alloc((size_t)NCOLS * 96 * 2);
    bf16_t* BeffT = (bf16_t*)alloc((size_t)3200 * UNITS * 2);
    bf16_t* x0    = (bf16_t*)alloc((size_t)MROWS * 96 * 2);
    bf16_t* h0    = (bf16_t*)alloc((size_t)MROWS * UNITS * 2);
    bf16_t* h1    = (bf16_t*)alloc((size_t)MROWS * UNITS * 2);
    float*  cst   = (float*)alloc((size_t)MROWS * UNITS * 4);  // tile-major layout
    float*  b0r   = (float*)alloc(NCOLS * 4);
    float*  beffr = (float*)alloc(NCOLS * 4);

    prep_b0   <<<(NCOLS * 96 + 255) / 256, 256, 0, stream>>>(W_ih, B0T);
    prep_x0   <<<(MROWS * 96) / 256, 256, 0, stream>>>(inputs, x0);
    prep_bias <<<(NCOLS + 255) / 256, 256, 0, stream>>>(b_ih, b_hh, W_ih, b_d, b0r, beffr);
    prep_beff2<<<dim3(48, 12), 256, 0, stream>>>(W_hh, W_ih, W_d, BeffT);
    prep_wdt  <<<(128 * UNITS) / 256, 256, 0, stream>>>(W_d, BeffT);

    bf16_t* h[2] = {h0, h1};

    // iter 0: gates from x0 (K=96), h=c=0, no pred tile (384 tiles)
    step_kernel<<<384, 256, 0, stream>>>(x0, B0T, b0r, b_d, cst, h[1], out, 96, 0, 0, 1);
    // iters 1..63: gates_n + pred_{n-1} columns (400 tiles, K=768)
    for (int n = 1; n < 64; ++n)
        step_kernel<<<400, 256, 0, stream>>>(h[n & 1], BeffT, beffr, b_d, cst,
                                             h[(n + 1) & 1], out, UNITS, 0, n, 0);
    // tail: pred_63 = h_64 @ W_d^T + b_d (pred tiles only, 16 tiles)
    step_kernel<<<16, 256, 0, stream>>>(h[0], BeffT, beffr, b_d, cst, h[1], out,
                                        UNITS, 24, 64, 0);
    (void)ws_size; (void)in_sizes; (void)n_in; (void)out_size;
}